// Round 8
// baseline (277.600 us; speedup 1.0000x reference)
//
#include <hip/hip_runtime.h>

#define NB 4
#define CB 64
#define HB 256
#define WB 256
#define OB 18
#define HWB (HB*WB)
#define TILE 16
#define HALFC 32
#define OPAD 12
#define WHALF (HALFC*OB*OPAD)   // 6912 floats per half, padded layout
#define EPSV 1e-5f

__device__ __forceinline__ int reflect_idx(int i, int n) {
    if (i < 0) i = -i;
    if (i >= n) i = 2*n - 2 - i;
    return i;
}

// Async global->LDS DMA, 4 bytes/lane. LDS dst is wave-uniform base + lane*4.
__device__ __forceinline__ void ldsdma4(const float* g, float* l) {
    __builtin_amdgcn_global_load_lds(
        (__attribute__((address_space(1))) unsigned int*)g,
        (__attribute__((address_space(3))) unsigned int*)l, 4, 0, 0);
}

// Transpose weights (18,64,3,3) -> wtp[c][o][12] (9 taps + 3 zero pad):
// 48B rows, 16B-aligned -> ds_read_b128-friendly once staged in LDS.
__global__ __launch_bounds__(256) void transpose_w_kernel(
    const float* __restrict__ w, float* __restrict__ wtp)
{
    int i = blockIdx.x * 256 + threadIdx.x;
    if (i < CB*OB*OPAD) {
        int c = i / (OB*OPAD);
        int r = i - c*OB*OPAD;
        int o = r / OPAD;
        int k = r - o*OPAD;
        wtp[i] = (k < 9) ? w[o*(CB*9) + c*9 + k] : 0.f;
    }
}

// 12 reflect-padded tap offsets covering TWO vertical pixels (rows h,h+1):
// tap rows h-1..h+2, cols w-1..w+1. Channel-invariant; computed once.
#define MAKE_OFFS12(h, w) do {                                         \
    int _ro[4], _co[3];                                                \
    _Pragma("unroll")                                                  \
    for (int _d = 0; _d < 4; ++_d)                                     \
        _ro[_d] = reflect_idx((h) - 1 + _d, HB) * WB;                  \
    _Pragma("unroll")                                                  \
    for (int _d = 0; _d < 3; ++_d)                                     \
        _co[_d] = reflect_idx((w) - 1 + _d, WB);                       \
    _Pragma("unroll")                                                  \
    for (int _dy = 0; _dy < 4; ++_dy)                                  \
        _Pragma("unroll")                                              \
        for (int _dx = 0; _dx < 3; ++_dx)                              \
            offs[_dy*3+_dx] = _ro[_dy] + _co[_dx];                     \
} while (0)

// Kernel 1: 3x3x(32 of 64)->18 conv + per-block sum/sumsq partials.
// Direct global tap loads (L1-resident, no tile staging — r6 win);
// 2 vertical px/thread (r7 win). NEW: weights in LDS (27.6KB, staged once,
// 6912=27*256 linear DMA). All-lane same-address ds_read is a HW broadcast;
// compiler interleaves counted lgkmcnt with FMAs — removes the SGPR-starved
// s_load convoy (162 dwords/channel >> 22 dwordx4 of free SGPR prefetch).
__global__ __launch_bounds__(256) void conv_stats_kernel(
    const float* __restrict__ y, const float* __restrict__ wtp,
    float* __restrict__ sigma0, float* __restrict__ sigma1,
    float* __restrict__ psum, float* __restrict__ psq)
{
    __shared__ __align__(16) float lw[WHALF];
    __shared__ float red[4][36];
    const int tid = threadIdx.x;
    const int tx = tid & 15, ty = tid >> 4;        // ty 0..15
    const int bx = blockIdx.x, by = blockIdx.y;
    const int n = blockIdx.z >> 1, half = blockIdx.z & 1;
    const int h = by*32 + 2*ty;                    // first of 2 rows
    const int w = bx*TILE + tx;

    // Stage this half's padded weights into LDS (one-time).
    {
        const float* wsrc = wtp + half*WHALF;
#pragma unroll
        for (int i = 0; i < 27; ++i)               // 27*256 == WHALF
            ldsdma4(wsrc + tid + i*256, lw + tid + i*256);
    }

    int offs[12];
    MAKE_OFFS12(h, w);

    const float* ybase = y + ((size_t)n*CB + half*HALFC)*HWB;
    float* const sg = half ? sigma1 : sigma0;

    float acc0[OB], acc1[OB];
#pragma unroll
    for (int o = 0; o < OB; ++o) { acc0[o] = 0.f; acc1[o] = 0.f; }

    __syncthreads();                               // weights landed

#pragma unroll 2
    for (int c = 0; c < HALFC; ++c) {
        const float* p = ybase + (size_t)c*HWB;
        float v[12];
#pragma unroll
        for (int k = 0; k < 12; ++k) v[k] = p[offs[k]];
        const float* wp = lw + c*(OB*OPAD);        // LDS, broadcast reads
#pragma unroll
        for (int o = 0; o < OB; ++o)
#pragma unroll
            for (int dy = 0; dy < 3; ++dy)
#pragma unroll
                for (int dx = 0; dx < 3; ++dx) {
                    const float w_ = wp[o*OPAD + dy*3 + dx];
                    acc0[o] = fmaf(v[dy*3 + dx],     w_, acc0[o]);
                    acc1[o] = fmaf(v[(dy+1)*3 + dx], w_, acc1[o]);
                }
    }

    const int q = h*WB + w;
#pragma unroll
    for (int o = 0; o < OB; ++o) {
        const size_t b = ((size_t)n*OB + o)*HWB + q;
        sg[b]      = acc0[o];
        sg[b + WB] = acc1[o];
    }

    const int lane = tid & 63, wv = tid >> 6;
#pragma unroll
    for (int o = 0; o < OB; ++o) {
        float s  = acc0[o] + acc1[o];
        float s2 = acc0[o]*acc0[o] + acc1[o]*acc1[o];
        for (int off = 32; off > 0; off >>= 1) {
            s  += __shfl_down(s,  off, 64);
            s2 += __shfl_down(s2, off, 64);
        }
        if (lane == 0) { red[wv][o] = s; red[wv][o + OB] = s2; }
    }
    __syncthreads();
    if (tid < 36) {
        float t = red[0][tid] + red[1][tid] + red[2][tid] + red[3][tid];
        const int bid = ((n*2 + half)*8 + by)*16 + bx;   // 0..1023
        if (tid < OB) psum[tid*1024 + bid] = t;
        else          psq[(tid-OB)*1024 + bid] = t;
    }
}

// Kernel 2: reduce 1024 partials per channel -> fused scale/shift
__global__ __launch_bounds__(256) void stats_kernel(
    const float* __restrict__ psum, const float* __restrict__ psq,
    const float* __restrict__ gamma, const float* __restrict__ beta,
    float* __restrict__ scale, float* __restrict__ shift)
{
    const int o = blockIdx.x;
    const int t = threadIdx.x;
    float s = 0.f, s2 = 0.f;
#pragma unroll
    for (int i = 0; i < 4; ++i) {
        s  += psum[o*1024 + t + i*256];
        s2 += psq [o*1024 + t + i*256];
    }
    for (int off = 32; off > 0; off >>= 1) {
        s  += __shfl_down(s,  off, 64);
        s2 += __shfl_down(s2, off, 64);
    }
    __shared__ float red[8];
    const int lane = t & 63, wv = t >> 6;
    if (lane == 0) { red[wv] = s; red[wv + 4] = s2; }
    __syncthreads();
    if (t == 0) {
        float S  = red[0] + red[1] + red[2] + red[3];
        float SS = red[4] + red[5] + red[6] + red[7];
        const float cnt = (float)(NB * HWB);
        float mean = S / cnt;
        float var  = SS / cnt - mean*mean;
        float sc = gamma[o] * rsqrtf(var + EPSV);
        scale[o] = sc;
        shift[o] = beta[o] - mean * sc;
    }
}

// Kernel 2.5: normalize + softmax over 18 -> v_map (a required output; the
// apply kernel re-reads it so each apply block only needs its group's 9 rows).
__global__ __launch_bounds__(256) void softmax_vmap_kernel(
    const float* __restrict__ sigma0, const float* __restrict__ sigma1,
    const float* __restrict__ scale, const float* __restrict__ shift,
    float* __restrict__ vmap)
{
    const int n = blockIdx.y;
    const int q = blockIdx.x * 256 + threadIdx.x;
    float z[OB];
#pragma unroll
    for (int o = 0; o < OB; ++o) {
        const size_t idx = ((size_t)n*OB + o)*HWB + q;
        z[o] = fmaf(sigma0[idx] + sigma1[idx], scale[o], shift[o]);
    }
    float m = z[0];
#pragma unroll
    for (int o = 1; o < OB; ++o) m = fmaxf(m, z[o]);
    float sum = 0.f;
#pragma unroll
    for (int o = 0; o < OB; ++o) { z[o] = __expf(z[o] - m); sum += z[o]; }
    const float rs = 1.f / sum;
#pragma unroll
    for (int o = 0; o < OB; ++o)
        vmap[((size_t)n*OB + o)*HWB + q] = z[o] * rs;
}

// Kernel 3: adaptive filter, direct-load, 2 vertical px/thread:
// per channel 12 tap loads -> 18 FMAs -> 2 stores. Block's channel half IS
// one softmax group -> only z[2][9] filter weights needed.
__global__ __launch_bounds__(256) void apply_kernel(
    const float* __restrict__ y, const float* __restrict__ vmap,
    float* __restrict__ out)
{
    const int tid = threadIdx.x;
    const int tx = tid & 15, ty = tid >> 4;
    const int bx = blockIdx.x, by = blockIdx.y;
    const int n = blockIdx.z >> 1, half = blockIdx.z & 1;  // group g == half
    const int h = by*32 + 2*ty;
    const int w = bx*TILE + tx;
    const int q = h*WB + w;

    int offs[12];
    MAKE_OFFS12(h, w);

    const float* ybase = y + ((size_t)n*CB + half*HALFC)*HWB;

    float z0[9], z1[9];
#pragma unroll
    for (int k = 0; k < 9; ++k) {
        const size_t b = ((size_t)n*OB + half*9 + k)*HWB + q;
        z0[k] = vmap[b];
        z1[k] = vmap[b + WB];
    }

    float* obase = out + ((size_t)n*CB + half*HALFC)*HWB;

#pragma unroll 2
    for (int c = 0; c < HALFC; ++c) {
        const float* p = ybase + (size_t)c*HWB;
        float v[12];
#pragma unroll
        for (int k = 0; k < 12; ++k) v[k] = p[offs[k]];
        float a0 = 0.f, a1 = 0.f;
#pragma unroll
        for (int dy = 0; dy < 3; ++dy)
#pragma unroll
            for (int dx = 0; dx < 3; ++dx) {
                const int k = dy*3 + dx;
                a0 = fmaf(v[dy*3 + dx],     z0[k], a0);
                a1 = fmaf(v[(dy+1)*3 + dx], z1[k], a1);
            }
        const size_t b = (size_t)c*HWB + q;
        obase[b]      = a0;
        obase[b + WB] = a1;
    }
}

extern "C" void kernel_launch(void* const* d_in, const int* in_sizes, int n_in,
                              void* d_out, int out_size, void* d_ws, size_t ws_size,
                              hipStream_t stream) {
    const float* y     = (const float*)d_in[0];
    const float* w     = (const float*)d_in[1];
    const float* gamma = (const float*)d_in[2];
    const float* beta  = (const float*)d_in[3];
    float* out = (float*)d_out;

    float* sigma0 = (float*)d_ws;                 // 4*18*65536 floats
    float* wtp    = sigma0 + (size_t)NB*OB*HWB;   // 64*18*12 = 13824
    float* psum   = wtp + CB*OB*OPAD;             // 18*1024
    float* psq    = psum + OB*1024;               // 18*1024
    float* scale  = psq  + OB*1024;               // 18
    float* shift  = scale + OB;                   // 18

    float* sigma1 = out;                          // out region is dead until apply
    float* vmap   = out + (size_t)NB*CB*HWB;

    dim3 block(256);
    transpose_w_kernel<<<dim3((CB*OB*OPAD + 255)/256), block, 0, stream>>>(w, wtp);
    conv_stats_kernel<<<dim3(16,8,8), block, 0, stream>>>(y, wtp, sigma0, sigma1, psum, psq);
    stats_kernel<<<dim3(OB), block, 0, stream>>>(psum, psq, gamma, beta, scale, shift);
    softmax_vmap_kernel<<<dim3(HWB/256, NB), block, 0, stream>>>(sigma0, sigma1, scale, shift, vmap);
    apply_kernel<<<dim3(16,8,8), block, 0, stream>>>(y, vmap, out);
}

// Round 9
// 248.082 us; speedup vs baseline: 1.1190x; 1.1190x over previous
//
#include <hip/hip_runtime.h>

#define NB 4
#define CB 64
#define HB 256
#define WB 256
#define OB 18
#define HWB (HB*WB)
#define HALFC 32
#define EPSV 1e-5f

__device__ __forceinline__ int reflect_idx(int i, int n) {
    if (i < 0) i = -i;
    if (i >= n) i = 2*n - 2 - i;
    return i;
}

// Transpose weights (18,64,3,3) -> wt[c][o][k] so the conv reads 162
// contiguous floats per input channel (block-uniform -> s_load path; r8
// showed LDS-staged weights are SLOWER — ds pipe costs more than s_load waits).
__global__ __launch_bounds__(256) void transpose_w_kernel(
    const float* __restrict__ w, float* __restrict__ wt)
{
    int i = blockIdx.x * 256 + threadIdx.x;
    if (i < OB*CB*9) {
        int o   = i / (CB*9);
        int rem = i - o*CB*9;
        int c   = rem / 9;
        int k   = rem - c*9;
        wt[c*OB*9 + o*9 + k] = w[i];
    }
}

// 16 reflect-padded tap offsets covering a 2x2 pixel quad (rows h,h+1 x
// cols w,w+1): tap rows h-1..h+2, cols w-1..w+2. Channel-invariant.
#define MAKE_OFFS16(h, w) do {                                         \
    int _ro[4], _co[4];                                                \
    _Pragma("unroll")                                                  \
    for (int _d = 0; _d < 4; ++_d) {                                   \
        _ro[_d] = reflect_idx((h) - 1 + _d, HB) * WB;                  \
        _co[_d] = reflect_idx((w) - 1 + _d, WB);                       \
    }                                                                  \
    _Pragma("unroll")                                                  \
    for (int _dy = 0; _dy < 4; ++_dy)                                  \
        _Pragma("unroll")                                              \
        for (int _dx = 0; _dx < 4; ++_dx)                              \
            offs[_dy*4+_dx] = _ro[_dy] + _co[_dx];                     \
} while (0)

// Kernel 1: 3x3x(32 of 64)->18 conv + per-block sum/sumsq partials.
// Direct global tap loads (r6), scalar uniform weights (r7), and now a
// 2x2 pixel quad per thread: 648 FMAs per channel against the SAME 162
// scalar weight dwords -> scalar-wait per FMA halves vs r7; 16 tap loads
// serve 4 pixels (4/px vs r7's 6/px).
__global__ __launch_bounds__(256) void conv_stats_kernel(
    const float* __restrict__ y, const float* __restrict__ wt,
    float* __restrict__ sigma0, float* __restrict__ sigma1,
    float* __restrict__ psum, float* __restrict__ psq)
{
    __shared__ float red[4][36];
    const int tid = threadIdx.x;
    const int tx = tid & 15, ty = tid >> 4;
    const int bx = blockIdx.x, by = blockIdx.y;
    const int n = blockIdx.z >> 1, half = blockIdx.z & 1;
    const int h = by*32 + 2*ty;                    // quad rows h,h+1
    const int w = bx*32 + 2*tx;                    // quad cols w,w+1

    int offs[16];
    MAKE_OFFS16(h, w);

    const float* ybase = y + ((size_t)n*CB + half*HALFC)*HWB;
    float* const sg = half ? sigma1 : sigma0;

    float acc[4][OB];                              // [jv*2+jh][o]
#pragma unroll
    for (int j = 0; j < 4; ++j)
#pragma unroll
        for (int o = 0; o < OB; ++o) acc[j][o] = 0.f;

#pragma unroll 2
    for (int c = 0; c < HALFC; ++c) {
        const float* p = ybase + (size_t)c*HWB;
        float v[16];
#pragma unroll
        for (int k = 0; k < 16; ++k) v[k] = p[offs[k]];
        const float* wp = wt + (half*HALFC + c)*162;   // uniform -> s_load
#pragma unroll
        for (int o = 0; o < OB; ++o)
#pragma unroll
            for (int dy = 0; dy < 3; ++dy)
#pragma unroll
                for (int dx = 0; dx < 3; ++dx) {
                    const float w_ = wp[o*9 + dy*3 + dx];
                    acc[0][o] = fmaf(v[dy*4 + dx],       w_, acc[0][o]);
                    acc[1][o] = fmaf(v[dy*4 + dx + 1],   w_, acc[1][o]);
                    acc[2][o] = fmaf(v[(dy+1)*4 + dx],   w_, acc[2][o]);
                    acc[3][o] = fmaf(v[(dy+1)*4 + dx+1], w_, acc[3][o]);
                }
    }

    const int q = h*WB + w;
#pragma unroll
    for (int o = 0; o < OB; ++o) {
        const size_t b = ((size_t)n*OB + o)*HWB + q;
        *(float2*)(sg + b)      = make_float2(acc[0][o], acc[1][o]);
        *(float2*)(sg + b + WB) = make_float2(acc[2][o], acc[3][o]);
    }

    const int lane = tid & 63, wv = tid >> 6;
#pragma unroll
    for (int o = 0; o < OB; ++o) {
        float s  = acc[0][o] + acc[1][o] + acc[2][o] + acc[3][o];
        float s2 = acc[0][o]*acc[0][o] + acc[1][o]*acc[1][o]
                 + acc[2][o]*acc[2][o] + acc[3][o]*acc[3][o];
        for (int off = 32; off > 0; off >>= 1) {
            s  += __shfl_down(s,  off, 64);
            s2 += __shfl_down(s2, off, 64);
        }
        if (lane == 0) { red[wv][o] = s; red[wv][o + OB] = s2; }
    }
    __syncthreads();
    if (tid < 36) {
        float t = red[0][tid] + red[1][tid] + red[2][tid] + red[3][tid];
        const int bid = ((n*2 + half)*8 + by)*8 + bx;   // 0..511
        if (tid < OB) psum[tid*512 + bid] = t;
        else          psq[(tid-OB)*512 + bid] = t;
    }
}

// Kernel 2: reduce 512 partials per channel -> fused scale/shift
__global__ __launch_bounds__(256) void stats_kernel(
    const float* __restrict__ psum, const float* __restrict__ psq,
    const float* __restrict__ gamma, const float* __restrict__ beta,
    float* __restrict__ scale, float* __restrict__ shift)
{
    const int o = blockIdx.x;
    const int t = threadIdx.x;
    float s  = psum[o*512 + t] + psum[o*512 + t + 256];
    float s2 = psq [o*512 + t] + psq [o*512 + t + 256];
    for (int off = 32; off > 0; off >>= 1) {
        s  += __shfl_down(s,  off, 64);
        s2 += __shfl_down(s2, off, 64);
    }
    __shared__ float red[8];
    const int lane = t & 63, wv = t >> 6;
    if (lane == 0) { red[wv] = s; red[wv + 4] = s2; }
    __syncthreads();
    if (t == 0) {
        float S  = red[0] + red[1] + red[2] + red[3];
        float SS = red[4] + red[5] + red[6] + red[7];
        const float cnt = (float)(NB * HWB);
        float mean = S / cnt;
        float var  = SS / cnt - mean*mean;
        float sc = gamma[o] * rsqrtf(var + EPSV);
        scale[o] = sc;
        shift[o] = beta[o] - mean * sc;
    }
}

// Kernel 2.5: normalize + softmax over 18 -> v_map (a required output; the
// apply kernel re-reads it so each apply block only needs its group's 9 rows).
__global__ __launch_bounds__(256) void softmax_vmap_kernel(
    const float* __restrict__ sigma0, const float* __restrict__ sigma1,
    const float* __restrict__ scale, const float* __restrict__ shift,
    float* __restrict__ vmap)
{
    const int n = blockIdx.y;
    const int q = blockIdx.x * 256 + threadIdx.x;
    float z[OB];
#pragma unroll
    for (int o = 0; o < OB; ++o) {
        const size_t idx = ((size_t)n*OB + o)*HWB + q;
        z[o] = fmaf(sigma0[idx] + sigma1[idx], scale[o], shift[o]);
    }
    float m = z[0];
#pragma unroll
    for (int o = 1; o < OB; ++o) m = fmaxf(m, z[o]);
    float sum = 0.f;
#pragma unroll
    for (int o = 0; o < OB; ++o) { z[o] = __expf(z[o] - m); sum += z[o]; }
    const float rs = 1.f / sum;
#pragma unroll
    for (int o = 0; o < OB; ++o)
        vmap[((size_t)n*OB + o)*HWB + q] = z[o] * rs;
}

// Kernel 3: adaptive filter, direct-load, 2x2 pixel quad per thread:
// per channel 16 tap loads -> 36 FMAs -> 2 float2 stores; z weights loaded
// once as float2 pairs. Block's channel half IS one softmax group.
__global__ __launch_bounds__(256) void apply_kernel(
    const float* __restrict__ y, const float* __restrict__ vmap,
    float* __restrict__ out)
{
    const int tid = threadIdx.x;
    const int tx = tid & 15, ty = tid >> 4;
    const int bx = blockIdx.x, by = blockIdx.y;
    const int n = blockIdx.z >> 1, half = blockIdx.z & 1;  // group g == half
    const int h = by*32 + 2*ty;
    const int w = bx*32 + 2*tx;
    const int q = h*WB + w;

    int offs[16];
    MAKE_OFFS16(h, w);

    const float* ybase = y + ((size_t)n*CB + half*HALFC)*HWB;

    float2 z0[9], z1[9];                           // per-pixel filter weights
#pragma unroll
    for (int k = 0; k < 9; ++k) {
        const size_t b = ((size_t)n*OB + half*9 + k)*HWB + q;
        z0[k] = *(const float2*)(vmap + b);
        z1[k] = *(const float2*)(vmap + b + WB);
    }

    float* obase = out + ((size_t)n*CB + half*HALFC)*HWB;

#pragma unroll 2
    for (int c = 0; c < HALFC; ++c) {
        const float* p = ybase + (size_t)c*HWB;
        float v[16];
#pragma unroll
        for (int k = 0; k < 16; ++k) v[k] = p[offs[k]];
        float a00 = 0.f, a01 = 0.f, a10 = 0.f, a11 = 0.f;
#pragma unroll
        for (int dy = 0; dy < 3; ++dy)
#pragma unroll
            for (int dx = 0; dx < 3; ++dx) {
                const int k = dy*3 + dx;
                a00 = fmaf(v[dy*4 + dx],       z0[k].x, a00);
                a01 = fmaf(v[dy*4 + dx + 1],   z0[k].y, a01);
                a10 = fmaf(v[(dy+1)*4 + dx],   z1[k].x, a10);
                a11 = fmaf(v[(dy+1)*4 + dx+1], z1[k].y, a11);
            }
        const size_t b = (size_t)c*HWB + q;
        *(float2*)(obase + b)      = make_float2(a00, a01);
        *(float2*)(obase + b + WB) = make_float2(a10, a11);
    }
}

extern "C" void kernel_launch(void* const* d_in, const int* in_sizes, int n_in,
                              void* d_out, int out_size, void* d_ws, size_t ws_size,
                              hipStream_t stream) {
    const float* y     = (const float*)d_in[0];
    const float* w     = (const float*)d_in[1];
    const float* gamma = (const float*)d_in[2];
    const float* beta  = (const float*)d_in[3];
    float* out = (float*)d_out;

    float* sigma0 = (float*)d_ws;                 // 4*18*65536 floats
    float* wt     = sigma0 + (size_t)NB*OB*HWB;   // 10368
    float* psum   = wt + OB*CB*9;                 // 18*512
    float* psq    = psum + OB*512;                // 18*512
    float* scale  = psq  + OB*512;                // 18
    float* shift  = scale + OB;                   // 18

    float* sigma1 = out;                          // out region is dead until apply
    float* vmap   = out + (size_t)NB*CB*HWB;

    dim3 block(256);
    transpose_w_kernel<<<dim3((OB*CB*9 + 255)/256), block, 0, stream>>>(w, wt);
    conv_stats_kernel<<<dim3(8,8,8), block, 0, stream>>>(y, wt, sigma0, sigma1, psum, psq);
    stats_kernel<<<dim3(OB), block, 0, stream>>>(psum, psq, gamma, beta, scale, shift);
    softmax_vmap_kernel<<<dim3(HWB/256, NB), block, 0, stream>>>(sigma0, sigma1, scale, shift, vmap);
    apply_kernel<<<dim3(8,8,8), block, 0, stream>>>(y, vmap, out);
}